// Round 7
// baseline (108.412 us; speedup 1.0000x reference)
//
#include <hip/hip_runtime.h>
#include <math.h>

#define DM1 63
#define WROW 64
#define RSIZE (DM1*WROW)   // 4032 floats per rel-side matrix
#define VSTR 68            // LDS row stride (272B: 16B-aligned per row)

typedef float f4 __attribute__((ext_vector_type(4)));

// d_ws float offsets: only W now
#define OFF_W   0u

__device__ __forceinline__ float qreduce(float d) {
#if __has_builtin(__builtin_amdgcn_mov_dpp)
    int t = __builtin_amdgcn_mov_dpp(__float_as_int(d), 0xB1, 0xF, 0xF, true); // quad xor1
    d += __int_as_float(t);
    t = __builtin_amdgcn_mov_dpp(__float_as_int(d), 0x4E, 0xF, 0xF, true);     // quad xor2
    d += __int_as_float(t);
    return d;
#else
    d += __shfl_xor(d, 1);
    d += __shfl_xor(d, 2);
    return d;
#endif
}

// ---------------- K01: fused gelu + scale + Householder product, all in LDS.
// v' = gelu(w)*sqrt(2/n) lives in LDS; step: row -= (row.v')*v'.
// 4 lanes per row, 16 cols per lane; quad reduce via DPP.
#define K1LOAD(V, s) do { const f4* _vp = (const f4*)(vbase + (size_t)(s) * VSTR); \
    V##0 = _vp[0]; V##1 = _vp[1]; V##2 = _vp[2]; V##3 = _vp[3]; } while(0)

#define K1STEP(V) do { \
    f4 q01 = w0*V##0 + w1*V##1; \
    f4 q23 = w2*V##2 + w3*V##3; \
    f4 q = q01 + q23; \
    float d = (q[0] + q[1]) + (q[2] + q[3]); \
    d = qreduce(d); \
    w0 -= d*V##0; w1 -= d*V##1; w2 -= d*V##2; w3 -= d*V##3; } while(0)

__global__ __launch_bounds__(256) void k01_fused(const float* __restrict__ rwh,
                                                 const float* __restrict__ rwt,
                                                 float* __restrict__ wg) {
    int rs = blockIdx.x;               // 0..1023 : side*512 + r
    int side = rs >> 9, r = rs & 511;
    const float* rw = (side ? rwt : rwh) + (size_t)r * 3969;
    __shared__ __align__(16) float vv[DM1 * VSTR];
    __shared__ float sc[64];
    int tid = threadIdx.x;             // 256 threads

    // phase 1: gelu into LDS
    for (int idx = tid; idx < 3969; idx += 256) {
        int s = idx / 63, j = idx - s * 63;
        float x = rw[idx];
        vv[s * VSTR + j] = 0.5f * x * (1.f + erff(x * 0.70710678118654752f));
    }
    if (tid < DM1) vv[tid * VSTR + 63] = 0.f;   // zero pad col 63
    __syncthreads();

    // phase 2: per-step scale sqrt(2/sum(v^2)); 4 lanes per step-row
    if (tid < 252) {
        int s = tid >> 2, p = tid & 3;
        const float* vr = &vv[s * VSTR + p * 16];
        float sum = 0.f;
        #pragma unroll
        for (int j = 0; j < 16; j++) { float v = vr[j]; sum = fmaf(v, v, sum); }
        sum = qreduce(sum);
        if (p == 0) sc[s] = sqrtf(2.f / sum);
    }
    __syncthreads();

    // phase 3: pre-scale rows in place (col 63 stays 0)
    for (int idx = tid; idx < DM1 * 64; idx += 256) {
        int s = idx >> 6, j = idx & 63;
        vv[s * VSTR + j] *= sc[s];
    }
    __syncthreads();

    // phase 4: Householder product from LDS
    int lane = tid & 63, wv = tid >> 6;
    int row = wv * 16 + (lane >> 2);   // 0..63 (row 63 is a dummy)
    int p = lane & 3;                  // column quarter
    int c0 = p * 16;
    const float* vbase = &vv[c0];

    f4 w0, w1, w2, w3;
    #define IW(k, b) (((b) + (k)) == row ? 1.f : 0.f)
    w0 = (f4){IW(0,c0),    IW(1,c0),    IW(2,c0),    IW(3,c0)};
    w1 = (f4){IW(0,c0+4),  IW(1,c0+4),  IW(2,c0+4),  IW(3,c0+4)};
    w2 = (f4){IW(0,c0+8),  IW(1,c0+8),  IW(2,c0+8),  IW(3,c0+8)};
    w3 = (f4){IW(0,c0+12), IW(1,c0+12), IW(2,c0+12), IW(3,c0+12)};
    #undef IW

    f4 va0,va1,va2,va3, vb0,vb1,vb2,vb3, vc0,vc1,vc2,vc3, vd0,vd1,vd2,vd3;
    K1LOAD(va, 0); K1LOAD(vb, 1); K1LOAD(vc, 2); K1LOAD(vd, 3);
    #pragma unroll 1
    for (int s = 0; s < 56; s += 4) {
        K1STEP(va); K1LOAD(va, s + 4);
        K1STEP(vb); K1LOAD(vb, s + 5);
        K1STEP(vc); K1LOAD(vc, s + 6);
        K1STEP(vd); K1LOAD(vd, s + 7);
    }
    K1STEP(va); K1LOAD(va, 60);  // s=56
    K1STEP(vb); K1LOAD(vb, 61);  // s=57
    K1STEP(vc); K1LOAD(vc, 62);  // s=58
    K1STEP(vd);                  // s=59
    K1STEP(va);                  // s=60
    K1STEP(vb);                  // s=61
    K1STEP(vc);                  // s=62

    if (row < DM1) {
        f4* wo = (f4*)(wg + (size_t)rs * RSIZE + (size_t)row * WROW + c0);
        wo[0] = w0; wo[1] = w1; wo[2] = w2; wo[3] = w3;
    }
}

// ---------------- K3 mega: per-block prologue computes th (head transform,
// 4-wave-split dot) + tail boost constants in LDS, then scores 256 candidates.
__global__ __launch_bounds__(256) void k3_score(
    const int* __restrict__ pos, const int* __restrict__ neg,
    const float* __restrict__ emb, const float* __restrict__ bh,
    const float* __restrict__ bt, const float* __restrict__ wg,
    const float* __restrict__ bwh, const float* __restrict__ bwt,
    float* __restrict__ out) {
    __shared__ float th_lds[64];
    __shared__ float ro_lds[64];
    __shared__ float zk_lds[2];
    __shared__ float part[4][64];

    int b = blockIdx.x, j = threadIdx.x;
    int w = j >> 6, c = j & 63;
    int u = pos[b * 3], r = pos[b * 3 + 1];
    const float* hrow = emb + (size_t)u * 64;           // wave-uniform -> scalar
    const float* wh = wg + (size_t)r * RSIZE;           // head-side W

    // ---- prologue A: head-rotation partials, wave w covers d = 16w..16w+15
    {
        int d0 = w * 16, dend = (w == 3) ? 63 : d0 + 16;
        float xp = 0.f;
        for (int d = d0; d < dend; d++) xp = fmaf(hrow[1 + d], wh[d * WROW + c], xp);
        part[w][c] = xp;
    }
    // ---- prologue B (wave 0): tail boost constants
    if (w == 0) {
        float rov = (c < 63) ? tanhf(bwt[r * 63 + c]) * 0.015625f : 0.f;
        ro_lds[c] = rov;
        float p = rov * rov;
        #pragma unroll
        for (int off = 32; off; off >>= 1) p += __shfl_xor(p, off);
        if (c == 0) {
            float v2 = p;
            float zeta = 1.f / (sqrtf(1.f - v2) + 1e-8f);
            zk_lds[0] = zeta;
            zk_lds[1] = (zeta - 1.f) / (v2 + 1e-9f);
        }
    }
    __syncthreads();
    // ---- prologue C (wave 1): finish head transform th = boost(rot(h))
    if (w == 1) {
        float xnc = (part[0][c] + part[1][c]) + (part[2][c] + part[3][c]);
        float rov = (c < 63) ? tanhf(bwh[r * 63 + c]) * 0.015625f : 0.f;
        float p = rov * rov, q = xnc * rov;
        #pragma unroll
        for (int off = 32; off; off >>= 1) { p += __shfl_xor(p, off); q += __shfl_xor(q, off); }
        float v2 = p, dot = q;
        float zeta = 1.f / (sqrtf(1.f - v2) + 1e-8f);
        float k = (zeta - 1.f) / (v2 + 1e-9f);
        float x0 = hrow[0];
        float val;
        int idx;
        if (c < 63) { val = fmaf(-zeta * x0, rov, xnc) + k * rov * dot; idx = c + 1; }
        else        { val = zeta * x0 - zeta * dot;                      idx = 0;    }
        th_lds[idx] = val;
    }
    __syncthreads();

    // ---- scoring: thread j = tail candidate j
    int v = (j == 0) ? pos[b * 3 + 2] : neg[b * 255 + j - 1];
    const float4* tp4 = (const float4*)(emb + (size_t)v * 64);
    const float* wt = wg + (size_t)(512 + r) * RSIZE;   // tail side
    const float* ro = ro_lds;                           // uniform LDS broadcast
    const float* th = th_lds;
    float zeta = zk_lds[0], kk = zk_lds[1];

    float xn[64];
    #pragma unroll
    for (int cc = 0; cc < 64; cc++) xn[cc] = 0.f;
    float x0;
    {   // peel q=0: elements t[0..3] -> x0 and d=0,1,2
        float4 tv = tp4[0];
        x0 = tv.x;
        #pragma unroll
        for (int cc = 0; cc < 64; cc++) xn[cc] = fmaf(tv.y, wt[cc], xn[cc]);
        #pragma unroll
        for (int cc = 0; cc < 64; cc++) xn[cc] = fmaf(tv.z, wt[64 + cc], xn[cc]);
        #pragma unroll
        for (int cc = 0; cc < 64; cc++) xn[cc] = fmaf(tv.w, wt[128 + cc], xn[cc]);
    }
    #pragma unroll 1
    for (int q = 1; q < 16; q++) {      // d = 4q-1 .. 4q+2
        float4 tv = tp4[q];
        const float* wq = wt + (4 * q - 1) * 64;
        #pragma unroll
        for (int cc = 0; cc < 64; cc++) xn[cc] = fmaf(tv.x, wq[cc], xn[cc]);
        #pragma unroll
        for (int cc = 0; cc < 64; cc++) xn[cc] = fmaf(tv.y, wq[64 + cc], xn[cc]);
        #pragma unroll
        for (int cc = 0; cc < 64; cc++) xn[cc] = fmaf(tv.z, wq[128 + cc], xn[cc]);
        #pragma unroll
        for (int cc = 0; cc < 64; cc++) xn[cc] = fmaf(tv.w, wq[192 + cc], xn[cc]);
    }
    // boost(tail) + score. ro[63]=0, xn[63]=0 (W col 63 zeroed).
    float dot = 0.f;
    #pragma unroll
    for (int cc = 0; cc < 64; cc++) dot = fmaf(xn[cc], ro[cc], dot);
    float tt0 = zeta * x0 - zeta * dot;
    float d0 = tt0 - th[0];
    float acc = -d0 * d0;
    float A = fmaf(kk, dot, -zeta * x0);   // tt[1+c] = xn[c] + A*ro[c]
    #pragma unroll
    for (int cc = 0; cc < 63; cc++) {
        float ttc = fmaf(A, ro[cc], xn[cc]);
        float dd = ttc - th[1 + cc];
        acc = fmaf(dd, dd, acc);
    }
    out[b * 256 + j] = 0.85f - acc + tanhf(bh[u]) + tanhf(bt[v]);
}

extern "C" void kernel_launch(void* const* d_in, const int* in_sizes, int n_in,
                              void* d_out, int out_size, void* d_ws, size_t ws_size,
                              hipStream_t stream) {
    const int*   pos = (const int*)d_in[0];
    const int*   neg = (const int*)d_in[1];
    const float* emb = (const float*)d_in[2];
    const float* bh  = (const float*)d_in[3];
    const float* bt  = (const float*)d_in[4];
    const float* rwh = (const float*)d_in[5];
    const float* bwh = (const float*)d_in[6];
    const float* rwt = (const float*)d_in[7];
    const float* bwt = (const float*)d_in[8];
    float* wgp = (float*)d_ws + OFF_W;
    float* out = (float*)d_out;

    k01_fused<<<dim3(1024), dim3(256), 0, stream>>>(rwh, rwt, wgp);
    k3_score <<<dim3(1024), dim3(256), 0, stream>>>(pos, neg, emb, bh, bt, wgp,
                                                    bwh, bwt, out);
}

// Round 8
// 98.518 us; speedup vs baseline: 1.1004x; 1.1004x over previous
//
#include <hip/hip_runtime.h>
#include <math.h>

#define DM1 63
#define WROW 64
#define RSIZE (DM1*WROW)   // 4032 floats per rel-side matrix
#define VSTR 68            // k01 LDS row stride (272B: 16B-aligned per row)

typedef float f4 __attribute__((ext_vector_type(4)));

// d_ws float offsets
#define OFF_W   0u
#define SZ_W    (1024u*RSIZE)
#define OFF_TH  (OFF_W + SZ_W)
#define SZ_TH   (1024u*64u)
#define OFF_RO  (OFF_TH + SZ_TH)
#define SZ_RO   (512u*64u)
#define OFF_ZK  (OFF_RO + SZ_RO)

__device__ __forceinline__ float qreduce(float d) {
#if __has_builtin(__builtin_amdgcn_mov_dpp)
    int t = __builtin_amdgcn_mov_dpp(__float_as_int(d), 0xB1, 0xF, 0xF, true); // quad xor1
    d += __int_as_float(t);
    t = __builtin_amdgcn_mov_dpp(__float_as_int(d), 0x4E, 0xF, 0xF, true);     // quad xor2
    d += __int_as_float(t);
    return d;
#else
    d += __shfl_xor(d, 1);
    d += __shfl_xor(d, 2);
    return d;
#endif
}

// ---------------- K01: fused gelu + scale + Householder product, all in LDS.
#define K1LOAD(V, s) do { const f4* _vp = (const f4*)(vbase + (size_t)(s) * VSTR); \
    V##0 = _vp[0]; V##1 = _vp[1]; V##2 = _vp[2]; V##3 = _vp[3]; } while(0)

#define K1STEP(V) do { \
    f4 q01 = w0*V##0 + w1*V##1; \
    f4 q23 = w2*V##2 + w3*V##3; \
    f4 q = q01 + q23; \
    float d = (q[0] + q[1]) + (q[2] + q[3]); \
    d = qreduce(d); \
    w0 -= d*V##0; w1 -= d*V##1; w2 -= d*V##2; w3 -= d*V##3; } while(0)

__global__ __launch_bounds__(256) void k01_fused(const float* __restrict__ rwh,
                                                 const float* __restrict__ rwt,
                                                 float* __restrict__ wg) {
    int rs = blockIdx.x;               // 0..1023 : side*512 + r
    int side = rs >> 9, r = rs & 511;
    const float* rw = (side ? rwt : rwh) + (size_t)r * 3969;
    __shared__ __align__(16) float vv[DM1 * VSTR];
    __shared__ float sc[64];
    int tid = threadIdx.x;             // 256 threads

    for (int idx = tid; idx < 3969; idx += 256) {
        int s = idx / 63, j = idx - s * 63;
        float x = rw[idx];
        vv[s * VSTR + j] = 0.5f * x * (1.f + erff(x * 0.70710678118654752f));
    }
    if (tid < DM1) vv[tid * VSTR + 63] = 0.f;   // zero pad col 63
    __syncthreads();

    if (tid < 252) {
        int s = tid >> 2, p = tid & 3;
        const float* vr = &vv[s * VSTR + p * 16];
        float sum = 0.f;
        #pragma unroll
        for (int j = 0; j < 16; j++) { float v = vr[j]; sum = fmaf(v, v, sum); }
        sum = qreduce(sum);
        if (p == 0) sc[s] = sqrtf(2.f / sum);
    }
    __syncthreads();

    for (int idx = tid; idx < DM1 * 64; idx += 256) {
        int s = idx >> 6, j = idx & 63;
        vv[s * VSTR + j] *= sc[s];
    }
    __syncthreads();

    int lane = tid & 63, wv = tid >> 6;
    int row = wv * 16 + (lane >> 2);   // 0..63 (row 63 is a dummy)
    int p = lane & 3;
    int c0 = p * 16;
    const float* vbase = &vv[c0];

    f4 w0, w1, w2, w3;
    #define IW(k, b) (((b) + (k)) == row ? 1.f : 0.f)
    w0 = (f4){IW(0,c0),    IW(1,c0),    IW(2,c0),    IW(3,c0)};
    w1 = (f4){IW(0,c0+4),  IW(1,c0+4),  IW(2,c0+4),  IW(3,c0+4)};
    w2 = (f4){IW(0,c0+8),  IW(1,c0+8),  IW(2,c0+8),  IW(3,c0+8)};
    w3 = (f4){IW(0,c0+12), IW(1,c0+12), IW(2,c0+12), IW(3,c0+12)};
    #undef IW

    f4 va0,va1,va2,va3, vb0,vb1,vb2,vb3, vc0,vc1,vc2,vc3, vd0,vd1,vd2,vd3;
    K1LOAD(va, 0); K1LOAD(vb, 1); K1LOAD(vc, 2); K1LOAD(vd, 3);
    #pragma unroll 1
    for (int s = 0; s < 56; s += 4) {
        K1STEP(va); K1LOAD(va, s + 4);
        K1STEP(vb); K1LOAD(vb, s + 5);
        K1STEP(vc); K1LOAD(vc, s + 6);
        K1STEP(vd); K1LOAD(vd, s + 7);
    }
    K1STEP(va); K1LOAD(va, 60);
    K1STEP(vb); K1LOAD(vb, 61);
    K1STEP(vc); K1LOAD(vc, 62);
    K1STEP(vd);
    K1STEP(va);
    K1STEP(vb);
    K1STEP(vc);

    if (row < DM1) {
        f4* wo = (f4*)(wg + (size_t)rs * RSIZE + (size_t)row * WROW + c0);
        wo[0] = w0; wo[1] = w1; wo[2] = w2; wo[3] = w3;
    }
}

// ---------------- K_ro: tail boost constants per relation
__global__ void k_ro(const float* __restrict__ bwt, float* __restrict__ rog,
                     float* __restrict__ zkg) {
    int r = blockIdx.x, c = threadIdx.x;   // 64 threads
    float rov = (c < 63) ? tanhf(bwt[r * 63 + c]) * 0.015625f : 0.f;
    rog[r * 64 + c] = rov;
    float p = rov * rov;
    #pragma unroll
    for (int off = 32; off; off >>= 1) p += __shfl_xor(p, off);
    if (c == 0) {
        float v2 = p;
        float zeta = 1.f / (sqrtf(1.f - v2) + 1e-8f);
        zkg[r * 2]     = zeta;
        zkg[r * 2 + 1] = (zeta - 1.f) / (v2 + 1e-9f);
    }
}

// ---------------- K2: head transform. Wave per b, 4 b's per block, no barriers.
__global__ __launch_bounds__(256) void k2_th(const int* __restrict__ pos,
                      const float* __restrict__ emb,
                      const float* __restrict__ wg, const float* __restrict__ bwh,
                      float* __restrict__ thg) {
    int tid = threadIdx.x;
    int b = blockIdx.x * 4 + (tid >> 6), c = tid & 63;
    int u = pos[b * 3], r = pos[b * 3 + 1];
    const float* hrow = emb + (size_t)u * 64;          // wave-uniform -> scalar
    const float* wr = wg + (size_t)r * RSIZE;          // head side
    float xnc = 0.f;
    for (int d = 0; d < DM1; d++) xnc = fmaf(hrow[1 + d], wr[d * WROW + c], xnc);
    float rov = (c < 63) ? tanhf(bwh[r * 63 + c]) * 0.015625f : 0.f;
    float p = rov * rov, q = xnc * rov;
    #pragma unroll
    for (int off = 32; off; off >>= 1) { p += __shfl_xor(p, off); q += __shfl_xor(q, off); }
    float v2 = p, dot = q;
    float zeta = 1.f / (sqrtf(1.f - v2) + 1e-8f);
    float k = (zeta - 1.f) / (v2 + 1e-9f);
    float x0 = hrow[0];
    float val;
    int idx;
    if (c < 63) { val = fmaf(-zeta * x0, rov, xnc) + k * rov * dot; idx = c + 1; }
    else        { val = zeta * x0 - zeta * dot;                      idx = 0;    }
    thg[b * 64 + idx] = val;
}

// ---------------- K3: scoring. W-tail staged in LDS (broadcast ds_reads),
// th/ro/zk staged in LDS. Thread = tail candidate.
__global__ __launch_bounds__(256) void k3_score(
    const int* __restrict__ pos, const int* __restrict__ neg,
    const float* __restrict__ emb, const float* __restrict__ bh,
    const float* __restrict__ bt, const float* __restrict__ wg,
    const float* __restrict__ thg, const float* __restrict__ rog,
    const float* __restrict__ zkg, float* __restrict__ out) {
    __shared__ __align__(16) float wl[RSIZE];     // 16128 B
    __shared__ __align__(16) float th_l[64];
    __shared__ __align__(16) float ro_l[64];
    __shared__ float zk_l[2];

    int b = blockIdx.x, j = threadIdx.x;
    int u = pos[b * 3], r = pos[b * 3 + 1];
    int v = (j == 0) ? pos[b * 3 + 2] : neg[b * 255 + j - 1];

    // stage W tail (1008 f4), th (16 f4), ro (16 f4), zk
    {
        const f4* src = (const f4*)(wg + (size_t)(512 + r) * RSIZE);
        f4* dst = (f4*)wl;
        for (int idx = j; idx < 1008; idx += 256) dst[idx] = src[idx];
        if (j < 16)        ((f4*)th_l)[j]      = ((const f4*)(thg + b * 64))[j];
        else if (j < 32)   ((f4*)ro_l)[j - 16] = ((const f4*)(rog + r * 64))[j - 16];
        else if (j == 32)  { zk_l[0] = zkg[2 * r]; zk_l[1] = zkg[2 * r + 1]; }
    }
    const float4* tp4 = (const float4*)(emb + (size_t)v * 64);
    float4 tv0 = tp4[0];                 // gather issue overlaps the staging
    __syncthreads();

    f4 xn[16];
    #pragma unroll
    for (int k = 0; k < 16; k++) xn[k] = (f4)0.f;
    float x0 = tv0.x;
    {   // rows 0..2
        const f4* wp = (const f4*)wl;
        #pragma unroll
        for (int k = 0; k < 16; k++) xn[k] += tv0.y * wp[k];
        #pragma unroll
        for (int k = 0; k < 16; k++) xn[k] += tv0.z * wp[16 + k];
        #pragma unroll
        for (int k = 0; k < 16; k++) xn[k] += tv0.w * wp[32 + k];
    }
    #pragma unroll 5
    for (int q = 1; q < 16; q++) {       // rows 4q-1 .. 4q+2
        float4 tv = tp4[q];
        const f4* wq = (const f4*)(wl + (4 * q - 1) * 64);
        #pragma unroll
        for (int k = 0; k < 16; k++) xn[k] += tv.x * wq[k];
        #pragma unroll
        for (int k = 0; k < 16; k++) xn[k] += tv.y * wq[16 + k];
        #pragma unroll
        for (int k = 0; k < 16; k++) xn[k] += tv.z * wq[32 + k];
        #pragma unroll
        for (int k = 0; k < 16; k++) xn[k] += tv.w * wq[48 + k];
    }
    // boost(tail) + score. ro[63]=0, xn col63=0.
    float zeta = zk_l[0], kk = zk_l[1];
    const f4* ro4 = (const f4*)ro_l;
    f4 da = (f4)0.f;
    #pragma unroll
    for (int k = 0; k < 16; k++) da += xn[k] * ro4[k];
    float dot = (da[0] + da[1]) + (da[2] + da[3]);
    float tt0 = zeta * x0 - zeta * dot;
    float d0 = tt0 - th_l[0];
    float acc = -d0 * d0;
    float A = fmaf(kk, dot, -zeta * x0);   // tt[1+c] = xn[c] + A*ro[c]
    #pragma unroll
    for (int c = 0; c < 63; c++) {
        float ttc = fmaf(A, ro_l[c], xn[c >> 2][c & 3]);
        float dd = ttc - th_l[1 + c];
        acc = fmaf(dd, dd, acc);
    }
    out[b * 256 + j] = 0.85f - acc + tanhf(bh[u]) + tanhf(bt[v]);
}

extern "C" void kernel_launch(void* const* d_in, const int* in_sizes, int n_in,
                              void* d_out, int out_size, void* d_ws, size_t ws_size,
                              hipStream_t stream) {
    const int*   pos = (const int*)d_in[0];
    const int*   neg = (const int*)d_in[1];
    const float* emb = (const float*)d_in[2];
    const float* bh  = (const float*)d_in[3];
    const float* bt  = (const float*)d_in[4];
    const float* rwh = (const float*)d_in[5];
    const float* bwh = (const float*)d_in[6];
    const float* rwt = (const float*)d_in[7];
    const float* bwt = (const float*)d_in[8];
    float* ws  = (float*)d_ws;
    float* wgp = ws + OFF_W;
    float* thg = ws + OFF_TH;
    float* rog = ws + OFF_RO;
    float* zkg = ws + OFF_ZK;
    float* out = (float*)d_out;

    k01_fused<<<dim3(1024), dim3(256), 0, stream>>>(rwh, rwt, wgp);
    k_ro     <<<dim3(512),  dim3(64),  0, stream>>>(bwt, rog, zkg);
    k2_th    <<<dim3(256),  dim3(256), 0, stream>>>(pos, emb, wgp, bwh, thg);
    k3_score <<<dim3(1024), dim3(256), 0, stream>>>(pos, neg, emb, bh, bt, wgp,
                                                    thg, rog, zkg, out);
}

// Round 9
// 78.836 us; speedup vs baseline: 1.3752x; 1.2497x over previous
//
#include <hip/hip_runtime.h>
#include <math.h>

#define DM1 63
#define WROW 64
#define RSIZE (DM1*WROW)   // 4032 floats per rel-side matrix
#define VSTR 68            // k01 LDS row stride
#define TSTR 72            // bf16 LDS row stride (144B: 16B-aligned, conflict-free)

typedef float f4 __attribute__((ext_vector_type(4)));
typedef float f32x4 __attribute__((ext_vector_type(4)));
typedef short s16x8 __attribute__((ext_vector_type(8)));
typedef unsigned short u16x8 __attribute__((ext_vector_type(8)));

// d_ws float offsets
#define OFF_W   0u
#define SZ_W    (1024u*RSIZE)
#define OFF_TH  (OFF_W + SZ_W)
#define SZ_TH   (1024u*64u)
#define OFF_RO  (OFF_TH + SZ_TH)
#define SZ_RO   (512u*64u)
#define OFF_ZK  (OFF_RO + SZ_RO)

__device__ __forceinline__ float qreduce(float d) {
#if __has_builtin(__builtin_amdgcn_mov_dpp)
    int t = __builtin_amdgcn_mov_dpp(__float_as_int(d), 0xB1, 0xF, 0xF, true);
    d += __int_as_float(t);
    t = __builtin_amdgcn_mov_dpp(__float_as_int(d), 0x4E, 0xF, 0xF, true);
    d += __int_as_float(t);
    return d;
#else
    d += __shfl_xor(d, 1);
    d += __shfl_xor(d, 2);
    return d;
#endif
}

__device__ __forceinline__ unsigned short bf16rne(float x) {
    unsigned u = __float_as_uint(x);
    return (unsigned short)((u + 0x7FFFu + ((u >> 16) & 1u)) >> 16);
}

// ---------------- K01: fused gelu + scale + Householder product, all in LDS.
#define K1LOAD(V, s) do { const f4* _vp = (const f4*)(vbase + (size_t)(s) * VSTR); \
    V##0 = _vp[0]; V##1 = _vp[1]; V##2 = _vp[2]; V##3 = _vp[3]; } while(0)

#define K1STEP(V) do { \
    f4 q01 = w0*V##0 + w1*V##1; \
    f4 q23 = w2*V##2 + w3*V##3; \
    f4 q = q01 + q23; \
    float d = (q[0] + q[1]) + (q[2] + q[3]); \
    d = qreduce(d); \
    w0 -= d*V##0; w1 -= d*V##1; w2 -= d*V##2; w3 -= d*V##3; } while(0)

__global__ __launch_bounds__(256) void k01_fused(const float* __restrict__ rwh,
                                                 const float* __restrict__ rwt,
                                                 float* __restrict__ wg) {
    int rs = blockIdx.x;
    int side = rs >> 9, r = rs & 511;
    const float* rw = (side ? rwt : rwh) + (size_t)r * 3969;
    __shared__ __align__(16) float vv[DM1 * VSTR];
    __shared__ float sc[64];
    int tid = threadIdx.x;

    for (int idx = tid; idx < 3969; idx += 256) {
        int s = idx / 63, j = idx - s * 63;
        float x = rw[idx];
        vv[s * VSTR + j] = 0.5f * x * (1.f + erff(x * 0.70710678118654752f));
    }
    if (tid < DM1) vv[tid * VSTR + 63] = 0.f;
    __syncthreads();

    if (tid < 252) {
        int s = tid >> 2, p = tid & 3;
        const float* vr = &vv[s * VSTR + p * 16];
        float sum = 0.f;
        #pragma unroll
        for (int j = 0; j < 16; j++) { float v = vr[j]; sum = fmaf(v, v, sum); }
        sum = qreduce(sum);
        if (p == 0) sc[s] = sqrtf(2.f / sum);
    }
    __syncthreads();

    for (int idx = tid; idx < DM1 * 64; idx += 256) {
        int s = idx >> 6, j = idx & 63;
        vv[s * VSTR + j] *= sc[s];
    }
    __syncthreads();

    int lane = tid & 63, wv = tid >> 6;
    int row = wv * 16 + (lane >> 2);
    int p = lane & 3;
    int c0 = p * 16;
    const float* vbase = &vv[c0];

    f4 w0, w1, w2, w3;
    #define IW(k, b) (((b) + (k)) == row ? 1.f : 0.f)
    w0 = (f4){IW(0,c0),    IW(1,c0),    IW(2,c0),    IW(3,c0)};
    w1 = (f4){IW(0,c0+4),  IW(1,c0+4),  IW(2,c0+4),  IW(3,c0+4)};
    w2 = (f4){IW(0,c0+8),  IW(1,c0+8),  IW(2,c0+8),  IW(3,c0+8)};
    w3 = (f4){IW(0,c0+12), IW(1,c0+12), IW(2,c0+12), IW(3,c0+12)};
    #undef IW

    f4 va0,va1,va2,va3, vb0,vb1,vb2,vb3, vc0,vc1,vc2,vc3, vd0,vd1,vd2,vd3;
    K1LOAD(va, 0); K1LOAD(vb, 1); K1LOAD(vc, 2); K1LOAD(vd, 3);
    #pragma unroll 1
    for (int s = 0; s < 56; s += 4) {
        K1STEP(va); K1LOAD(va, s + 4);
        K1STEP(vb); K1LOAD(vb, s + 5);
        K1STEP(vc); K1LOAD(vc, s + 6);
        K1STEP(vd); K1LOAD(vd, s + 7);
    }
    K1STEP(va); K1LOAD(va, 60);
    K1STEP(vb); K1LOAD(vb, 61);
    K1STEP(vc); K1LOAD(vc, 62);
    K1STEP(vd);
    K1STEP(va);
    K1STEP(vb);
    K1STEP(vc);

    if (row < DM1) {
        f4* wo = (f4*)(wg + (size_t)rs * RSIZE + (size_t)row * WROW + c0);
        wo[0] = w0; wo[1] = w1; wo[2] = w2; wo[3] = w3;
    }
}

// ---------------- K_ro: tail boost constants per relation
__global__ void k_ro(const float* __restrict__ bwt, float* __restrict__ rog,
                     float* __restrict__ zkg) {
    int r = blockIdx.x, c = threadIdx.x;
    float rov = (c < 63) ? tanhf(bwt[r * 63 + c]) * 0.015625f : 0.f;
    rog[r * 64 + c] = rov;
    float p = rov * rov;
    #pragma unroll
    for (int off = 32; off; off >>= 1) p += __shfl_xor(p, off);
    if (c == 0) {
        float v2 = p;
        float zeta = 1.f / (sqrtf(1.f - v2) + 1e-8f);
        zkg[r * 2]     = zeta;
        zkg[r * 2 + 1] = (zeta - 1.f) / (v2 + 1e-9f);
    }
}

// ---------------- K2: head transform. Wave per b, 4 b's per block.
__global__ __launch_bounds__(256) void k2_th(const int* __restrict__ pos,
                      const float* __restrict__ emb,
                      const float* __restrict__ wg, const float* __restrict__ bwh,
                      float* __restrict__ thg) {
    int tid = threadIdx.x;
    int b = blockIdx.x * 4 + (tid >> 6), c = tid & 63;
    int u = pos[b * 3], r = pos[b * 3 + 1];
    const float* hrow = emb + (size_t)u * 64;
    const float* wr = wg + (size_t)r * RSIZE;
    float xnc = 0.f;
    for (int d = 0; d < DM1; d++) xnc = fmaf(hrow[1 + d], wr[d * WROW + c], xnc);
    float rov = (c < 63) ? tanhf(bwh[r * 63 + c]) * 0.015625f : 0.f;
    float p = rov * rov, q = xnc * rov;
    #pragma unroll
    for (int off = 32; off; off >>= 1) { p += __shfl_xor(p, off); q += __shfl_xor(q, off); }
    float v2 = p, dot = q;
    float zeta = 1.f / (sqrtf(1.f - v2) + 1e-8f);
    float k = (zeta - 1.f) / (v2 + 1e-9f);
    float x0 = hrow[0];
    float val;
    int idx;
    if (c < 63) { val = fmaf(-zeta * x0, rov, xnc) + k * rov * dot; idx = c + 1; }
    else        { val = zeta * x0 - zeta * dot;                      idx = 0;    }
    thg[b * 64 + idx] = val;
}

// ---------------- K3: MFMA scoring. Per block: 256 cand x 64 col x K=64 GEMM.
// t rows bf16 (k=0 row of B is zero so t[0] rounding is inert); W in bf16 hi+lo.
__global__ __launch_bounds__(256) void k3_score(
    const int* __restrict__ pos, const int* __restrict__ neg,
    const float* __restrict__ emb, const float* __restrict__ bh,
    const float* __restrict__ bt, const float* __restrict__ wg,
    const float* __restrict__ thg, const float* __restrict__ rog,
    const float* __restrict__ zkg, float* __restrict__ out) {
    __shared__ __align__(16) unsigned short t_h[256 * TSTR];   // 36864 B
    __shared__ __align__(16) unsigned short w_h[64 * TSTR];    // 9216 B
    __shared__ __align__(16) unsigned short w_l[64 * TSTR];    // 9216 B
    __shared__ float x0_l[256];
    __shared__ float bt_l[256];
    __shared__ float th_l[64];
    __shared__ float ro_l[64];
    __shared__ float zk_l[2];

    int b = blockIdx.x, j = threadIdx.x;
    int u = pos[b * 3], r = pos[b * 3 + 1];
    int v = (j == 0) ? pos[b * 3 + 2] : neg[b * 255 + j - 1];

    // ---- stage t row (bf16) + x0 + tanh(bt[v])
    {
        const float4* tp4 = (const float4*)(emb + (size_t)v * 64);
        #pragma unroll
        for (int q = 0; q < 16; q += 2) {
            float4 a = tp4[q], c2 = tp4[q + 1];
            if (q == 0) x0_l[j] = a.x;
            u16x8 pk;
            pk[0] = bf16rne(a.x);  pk[1] = bf16rne(a.y);
            pk[2] = bf16rne(a.z);  pk[3] = bf16rne(a.w);
            pk[4] = bf16rne(c2.x); pk[5] = bf16rne(c2.y);
            pk[6] = bf16rne(c2.z); pk[7] = bf16rne(c2.w);
            *(u16x8*)(&t_h[j * TSTR + q * 4]) = pk;
        }
        bt_l[j] = tanhf(bt[v]);
    }
    // ---- stage W^T hi/lo: Wt[n][k] = (k==0) ? 0 : W[k-1][n]   (coalesced reads)
    {
        const float* wgt = wg + (size_t)(512 + r) * RSIZE;
        for (int idx = j; idx < 4096; idx += 256) {
            int k = idx >> 6, n = idx & 63;
            float val = (k == 0) ? 0.f : wgt[(k - 1) * 64 + n];
            unsigned short hi = bf16rne(val);
            float rem = val - __uint_as_float(((unsigned)hi) << 16);
            w_h[n * TSTR + k] = hi;
            w_l[n * TSTR + k] = bf16rne(rem);
        }
        if (j < 64)            th_l[j] = thg[b * 64 + j];
        else if (j < 128)      ro_l[j - 64] = rog[r * 64 + (j - 64)];
        else if (j == 128)     { zk_l[0] = zkg[2 * r]; zk_l[1] = zkg[2 * r + 1]; }
    }
    __syncthreads();

    // ---- MFMA: wave wv owns cands [64wv, 64wv+64). acc[mi][ni], 16x16 tiles.
    int lane = j & 63, wv = j >> 6;
    int g = lane >> 4, m = lane & 15;
    f32x4 acc[4][4] = {};
    #pragma unroll
    for (int kk = 0; kk < 2; kk++) {
        s16x8 bh_[4], bl_[4];
        #pragma unroll
        for (int ni = 0; ni < 4; ni++) {
            bh_[ni] = *(const s16x8*)(&w_h[(16 * ni + m) * TSTR + 32 * kk + 8 * g]);
            bl_[ni] = *(const s16x8*)(&w_l[(16 * ni + m) * TSTR + 32 * kk + 8 * g]);
        }
        #pragma unroll
        for (int mi = 0; mi < 4; mi++) {
            s16x8 af = *(const s16x8*)(&t_h[(64 * wv + 16 * mi + m) * TSTR + 32 * kk + 8 * g]);
            #pragma unroll
            for (int ni = 0; ni < 4; ni++) {
                acc[mi][ni] = __builtin_amdgcn_mfma_f32_16x16x32_bf16(af, bh_[ni], acc[mi][ni], 0, 0, 0);
                acc[mi][ni] = __builtin_amdgcn_mfma_f32_16x16x32_bf16(af, bl_[ni], acc[mi][ni], 0, 0, 0);
            }
        }
    }

    // ---- epilogue: C/D map: cand = 64wv+16mi+4g+reg, col = 16ni+m
    float zeta = zk_l[0], kz = zk_l[1];
    float th0 = th_l[0];
    float bhu = tanhf(bh[u]);
    float ro_reg[4], th_reg[4];
    #pragma unroll
    for (int ni = 0; ni < 4; ni++) {
        int col = 16 * ni + m;
        ro_reg[ni] = ro_l[col];
        th_reg[ni] = (col == 63) ? 0.f : th_l[1 + col];
    }
    #pragma unroll
    for (int mi = 0; mi < 4; mi++) {
        #pragma unroll
        for (int rg = 0; rg < 4; rg++) {
            int cand = 64 * wv + 16 * mi + 4 * g + rg;
            float pd = acc[mi][0][rg] * ro_reg[0] + acc[mi][1][rg] * ro_reg[1]
                     + acc[mi][2][rg] * ro_reg[2] + acc[mi][3][rg] * ro_reg[3];
            pd += __shfl_xor(pd, 1); pd += __shfl_xor(pd, 2);
            pd += __shfl_xor(pd, 4); pd += __shfl_xor(pd, 8);
            float x0 = x0_l[cand];
            float A = fmaf(kz, pd, -zeta * x0);
            float sq = 0.f;
            #pragma unroll
            for (int ni = 0; ni < 4; ni++) {
                float ttc = fmaf(A, ro_reg[ni], acc[mi][ni][rg]);
                float dd = ttc - th_reg[ni];
                sq = fmaf(dd, dd, sq);
            }
            sq += __shfl_xor(sq, 1); sq += __shfl_xor(sq, 2);
            sq += __shfl_xor(sq, 4); sq += __shfl_xor(sq, 8);
            float tt0 = zeta * x0 - zeta * pd;
            float d0 = tt0 - th0;
            float total = sq - d0 * d0;
            if (m == 0) out[b * 256 + cand] = 0.85f - total + bhu + bt_l[cand];
        }
    }
}

extern "C" void kernel_launch(void* const* d_in, const int* in_sizes, int n_in,
                              void* d_out, int out_size, void* d_ws, size_t ws_size,
                              hipStream_t stream) {
    const int*   pos = (const int*)d_in[0];
    const int*   neg = (const int*)d_in[1];
    const float* emb = (const float*)d_in[2];
    const float* bh  = (const float*)d_in[3];
    const float* bt  = (const float*)d_in[4];
    const float* rwh = (const float*)d_in[5];
    const float* bwh = (const float*)d_in[6];
    const float* rwt = (const float*)d_in[7];
    const float* bwt = (const float*)d_in[8];
    float* ws  = (float*)d_ws;
    float* wgp = ws + OFF_W;
    float* thg = ws + OFF_TH;
    float* rog = ws + OFF_RO;
    float* zkg = ws + OFF_ZK;
    float* out = (float*)d_out;

    k01_fused<<<dim3(1024), dim3(256), 0, stream>>>(rwh, rwt, wgp);
    k_ro     <<<dim3(512),  dim3(64),  0, stream>>>(bwt, rog, zkg);
    k2_th    <<<dim3(256),  dim3(256), 0, stream>>>(pos, emb, wgp, bwh, thg);
    k3_score <<<dim3(1024), dim3(256), 0, stream>>>(pos, neg, emb, bh, bt, wgp,
                                                    thg, rog, zkg, out);
}

// Round 10
// 65.461 us; speedup vs baseline: 1.6561x; 1.2043x over previous
//
#include <hip/hip_runtime.h>
#include <math.h>

#define DM1 63
#define WROW 64
#define RSIZE (DM1*WROW)   // 4032 floats per rel-side matrix
#define VSTR 68            // k01 LDS row stride

typedef float f4 __attribute__((ext_vector_type(4)));
typedef float f32x4 __attribute__((ext_vector_type(4)));
typedef short s16x8 __attribute__((ext_vector_type(8)));
typedef unsigned short u16x8 __attribute__((ext_vector_type(8)));

// d_ws float offsets
#define OFF_W   0u
#define SZ_W    (1024u*RSIZE)
#define OFF_TH  (OFF_W + SZ_W)
#define SZ_TH   (1024u*64u)
#define OFF_RO  (OFF_TH + SZ_TH)
#define SZ_RO   (512u*64u)
#define OFF_ZK  (OFF_RO + SZ_RO)

__device__ __forceinline__ float qreduce(float d) {
    int t = __builtin_amdgcn_mov_dpp(__float_as_int(d), 0xB1, 0xF, 0xF, true);
    d += __int_as_float(t);
    t = __builtin_amdgcn_mov_dpp(__float_as_int(d), 0x4E, 0xF, 0xF, true);
    d += __int_as_float(t);
    return d;
}

// 16-lane sum-reduce, broadcast to the 16 lanes. xor1/2 via DPP (VALU), 4/8 via shfl.
__device__ __forceinline__ float red16(float d) {
    int t = __builtin_amdgcn_mov_dpp(__float_as_int(d), 0xB1, 0xF, 0xF, true);
    d += __int_as_float(t);
    t = __builtin_amdgcn_mov_dpp(__float_as_int(d), 0x4E, 0xF, 0xF, true);
    d += __int_as_float(t);
    d += __shfl_xor(d, 4);
    d += __shfl_xor(d, 8);
    return d;
}

__device__ __forceinline__ unsigned short bf16rne(float x) {
    unsigned u = __float_as_uint(x);
    return (unsigned short)((u + 0x7FFFu + ((u >> 16) & 1u)) >> 16);
}

// ---------------- K01: fused gelu + scale + Householder product (+k_ro on side-1)
#define K1LOAD(V, s) do { const f4* _vp = (const f4*)(vbase + (size_t)(s) * VSTR); \
    V##0 = _vp[0]; V##1 = _vp[1]; V##2 = _vp[2]; V##3 = _vp[3]; } while(0)

#define K1STEP(V) do { \
    f4 q01 = w0*V##0 + w1*V##1; \
    f4 q23 = w2*V##2 + w3*V##3; \
    f4 q = q01 + q23; \
    float d = (q[0] + q[1]) + (q[2] + q[3]); \
    d = qreduce(d); \
    w0 -= d*V##0; w1 -= d*V##1; w2 -= d*V##2; w3 -= d*V##3; } while(0)

__global__ __launch_bounds__(256) void k01_fused(const float* __restrict__ rwh,
                                                 const float* __restrict__ rwt,
                                                 const float* __restrict__ bwt,
                                                 float* __restrict__ wg,
                                                 float* __restrict__ rog,
                                                 float* __restrict__ zkg) {
    int rs = blockIdx.x;
    int side = rs >> 9, r = rs & 511;
    const float* rw = (side ? rwt : rwh) + (size_t)r * 3969;
    __shared__ __align__(16) float vv[DM1 * VSTR];
    __shared__ float sc[64];
    int tid = threadIdx.x;

    // fold k_ro into side-1 blocks (independent of the rest; no extra sync)
    if (side && tid < 64) {
        int c = tid;
        float rov = (c < 63) ? tanhf(bwt[r * 63 + c]) * 0.015625f : 0.f;
        rog[r * 64 + c] = rov;
        float p = rov * rov;
        #pragma unroll
        for (int off = 32; off; off >>= 1) p += __shfl_xor(p, off);
        if (c == 0) {
            float v2 = p;
            float zeta = 1.f / (sqrtf(1.f - v2) + 1e-8f);
            zkg[r * 2]     = zeta;
            zkg[r * 2 + 1] = (zeta - 1.f) / (v2 + 1e-9f);
        }
    }

    for (int idx = tid; idx < 3969; idx += 256) {
        int s = idx / 63, j = idx - s * 63;
        float x = rw[idx];
        vv[s * VSTR + j] = 0.5f * x * (1.f + erff(x * 0.70710678118654752f));
    }
    if (tid < DM1) vv[tid * VSTR + 63] = 0.f;
    __syncthreads();

    if (tid < 252) {
        int s = tid >> 2, p = tid & 3;
        const float* vr = &vv[s * VSTR + p * 16];
        float sum = 0.f;
        #pragma unroll
        for (int j = 0; j < 16; j++) { float v = vr[j]; sum = fmaf(v, v, sum); }
        sum = qreduce(sum);
        if (p == 0) sc[s] = sqrtf(2.f / sum);
    }
    __syncthreads();

    for (int idx = tid; idx < DM1 * 64; idx += 256) {
        int s = idx >> 6, j = idx & 63;
        vv[s * VSTR + j] *= sc[s];
    }
    __syncthreads();

    int lane = tid & 63, wv = tid >> 6;
    int row = wv * 16 + (lane >> 2);
    int p = lane & 3;
    int c0 = p * 16;
    const float* vbase = &vv[c0];

    f4 w0, w1, w2, w3;
    #define IW(k, b) (((b) + (k)) == row ? 1.f : 0.f)
    w0 = (f4){IW(0,c0),    IW(1,c0),    IW(2,c0),    IW(3,c0)};
    w1 = (f4){IW(0,c0+4),  IW(1,c0+4),  IW(2,c0+4),  IW(3,c0+4)};
    w2 = (f4){IW(0,c0+8),  IW(1,c0+8),  IW(2,c0+8),  IW(3,c0+8)};
    w3 = (f4){IW(0,c0+12), IW(1,c0+12), IW(2,c0+12), IW(3,c0+12)};
    #undef IW

    f4 va0,va1,va2,va3, vb0,vb1,vb2,vb3, vc0,vc1,vc2,vc3, vd0,vd1,vd2,vd3;
    K1LOAD(va, 0); K1LOAD(vb, 1); K1LOAD(vc, 2); K1LOAD(vd, 3);
    #pragma unroll 1
    for (int s = 0; s < 56; s += 4) {
        K1STEP(va); K1LOAD(va, s + 4);
        K1STEP(vb); K1LOAD(vb, s + 5);
        K1STEP(vc); K1LOAD(vc, s + 6);
        K1STEP(vd); K1LOAD(vd, s + 7);
    }
    K1STEP(va); K1LOAD(va, 60);
    K1STEP(vb); K1LOAD(vb, 61);
    K1STEP(vc); K1LOAD(vc, 62);
    K1STEP(vd);
    K1STEP(va);
    K1STEP(vb);
    K1STEP(vc);

    if (row < DM1) {
        f4* wo = (f4*)(wg + (size_t)rs * RSIZE + (size_t)row * WROW + c0);
        wo[0] = w0; wo[1] = w1; wo[2] = w2; wo[3] = w3;
    }
}

// ---------------- K2: head transform. Wave per b, 4 b's per block.
__global__ __launch_bounds__(256) void k2_th(const int* __restrict__ pos,
                      const float* __restrict__ emb,
                      const float* __restrict__ wg, const float* __restrict__ bwh,
                      float* __restrict__ thg) {
    int tid = threadIdx.x;
    int b = blockIdx.x * 4 + (tid >> 6), c = tid & 63;
    int u = pos[b * 3], r = pos[b * 3 + 1];
    const float* hrow = emb + (size_t)u * 64;
    const float* wr = wg + (size_t)r * RSIZE;
    float xnc = 0.f;
    for (int d = 0; d < DM1; d++) xnc = fmaf(hrow[1 + d], wr[d * WROW + c], xnc);
    float rov = (c < 63) ? tanhf(bwh[r * 63 + c]) * 0.015625f : 0.f;
    float p = rov * rov, q = xnc * rov;
    #pragma unroll
    for (int off = 32; off; off >>= 1) { p += __shfl_xor(p, off); q += __shfl_xor(q, off); }
    float v2 = p, dot = q;
    float zeta = 1.f / (sqrtf(1.f - v2) + 1e-8f);
    float k = (zeta - 1.f) / (v2 + 1e-9f);
    float x0 = hrow[0];
    float val;
    int idx;
    if (c < 63) { val = fmaf(-zeta * x0, rov, xnc) + k * rov * dot; idx = c + 1; }
    else        { val = zeta * x0 - zeta * dot;                      idx = 0;    }
    thg[b * 64 + idx] = val;
}

// ---------------- K3: MFMA scoring with fragment-native LDS layout.
// tf chunk (wv,mi,kk): 64 lanes x 16B, addr = lane*16 -> conflict-free reads;
// staging writes land at 4m mod 32 -> 2-way (free).
__global__ __launch_bounds__(256) void k3_score(
    const int* __restrict__ pos, const int* __restrict__ neg,
    const float* __restrict__ emb, const float* __restrict__ bh,
    const float* __restrict__ bt, const float* __restrict__ wg,
    const float* __restrict__ thg, const float* __restrict__ rog,
    const float* __restrict__ zkg, float* __restrict__ out) {
    __shared__ __align__(16) unsigned short tf[16384];   // 32 KB: [wv][mi][kk][lane*8]
    __shared__ __align__(16) unsigned short wfh[4096];   // 8 KB: [ni][kk][lane*8]
    __shared__ __align__(16) unsigned short wfl[4096];   // 8 KB
    __shared__ float x0_l[256];
    __shared__ float bt_l[256];
    __shared__ float th_l[64];
    __shared__ float ro_l[64];
    __shared__ float zk_l[2];

    int b = blockIdx.x, j = threadIdx.x;
    int u = pos[b * 3], r = pos[b * 3 + 1];
    int v = (j == 0) ? pos[b * 3 + 2] : neg[b * 255 + j - 1];

    // ---- issue the random-row gather FIRST (HBM latency hides under W staging)
    const float4* tp4 = (const float4*)(emb + (size_t)v * 64);
    f4 trow[16];
    #pragma unroll
    for (int q = 0; q < 16; q++) trow[q] = *(const f4*)(&tp4[q]);
    float btv = bt[v];

    // ---- stage W^T hi/lo into fragment layout (coalesced global reads)
    {
        const float* wgt = wg + (size_t)(512 + r) * RSIZE;
        #pragma unroll
        for (int i = 0; i < 16; i++) {
            int idx = j + 256 * i;
            int k = idx >> 6, n = idx & 63;
            float val = (k == 0) ? 0.f : wgt[(k - 1) * 64 + n];
            unsigned short hi = bf16rne(val);
            float rem = val - __uint_as_float(((unsigned)hi) << 16);
            int di = (n >> 4) * 1024 + (k >> 5) * 512 + (((k >> 3) & 3) * 16 + (n & 15)) * 8 + (k & 7);
            wfh[di] = hi;
            wfl[di] = bf16rne(rem);
        }
        if (j < 64)            th_l[j] = thg[b * 64 + j];
        else if (j < 128)      ro_l[j - 64] = rog[r * 64 + (j - 64)];
        else if (j == 128)     { zk_l[0] = zkg[2 * r]; zk_l[1] = zkg[2 * r + 1]; }
    }

    // ---- convert + store t row into fragment layout
    {
        int base = (j >> 6) * 4096 + ((j >> 4) & 3) * 1024 + (j & 15) * 8;
        x0_l[j] = trow[0][0];
        bt_l[j] = tanhf(btv);
        #pragma unroll
        for (int q = 0; q < 16; q += 2) {       // cols 8q/2.. : kk=q>>3, g=(q>>1)&3
            f4 a = trow[q], c2 = trow[q + 1];
            u16x8 pk;
            pk[0] = bf16rne(a[0]);  pk[1] = bf16rne(a[1]);
            pk[2] = bf16rne(a[2]);  pk[3] = bf16rne(a[3]);
            pk[4] = bf16rne(c2[0]); pk[5] = bf16rne(c2[1]);
            pk[6] = bf16rne(c2[2]); pk[7] = bf16rne(c2[3]);
            *(u16x8*)(&tf[base + (q >> 3) * 512 + ((q >> 1) & 3) * 128]) = pk;
        }
    }
    __syncthreads();

    // ---- MFMA: wave wv owns cands [64wv, 64wv+64)
    int lane = j & 63, wv = j >> 6;
    int g = lane >> 4, m = lane & 15;
    f32x4 acc[4][4] = {};
    #pragma unroll
    for (int kk = 0; kk < 2; kk++) {
        s16x8 bh_[4], bl_[4];
        #pragma unroll
        for (int ni = 0; ni < 4; ni++) {
            bh_[ni] = *(const s16x8*)(&wfh[ni * 1024 + kk * 512 + lane * 8]);
            bl_[ni] = *(const s16x8*)(&wfl[ni * 1024 + kk * 512 + lane * 8]);
        }
        #pragma unroll
        for (int mi = 0; mi < 4; mi++) {
            s16x8 af = *(const s16x8*)(&tf[wv * 4096 + mi * 1024 + kk * 512 + lane * 8]);
            #pragma unroll
            for (int ni = 0; ni < 4; ni++) {
                acc[mi][ni] = __builtin_amdgcn_mfma_f32_16x16x32_bf16(af, bh_[ni], acc[mi][ni], 0, 0, 0);
                acc[mi][ni] = __builtin_amdgcn_mfma_f32_16x16x32_bf16(af, bl_[ni], acc[mi][ni], 0, 0, 0);
            }
        }
    }

    // ---- epilogue: cand = 64wv+16mi+4g+rg, col = 16ni+m
    float zeta = zk_l[0], kz = zk_l[1];
    float th0 = th_l[0];
    float bhu = tanhf(bh[u]);
    float ro_reg[4], th_reg[4];
    #pragma unroll
    for (int ni = 0; ni < 4; ni++) {
        int col = 16 * ni + m;
        ro_reg[ni] = ro_l[col];
        th_reg[ni] = (col == 63) ? 0.f : th_l[1 + col];
    }
    #pragma unroll
    for (int mi = 0; mi < 4; mi++) {
        #pragma unroll
        for (int rg = 0; rg < 4; rg++) {
            int cand = 64 * wv + 16 * mi + 4 * g + rg;
            float pd = acc[mi][0][rg] * ro_reg[0] + acc[mi][1][rg] * ro_reg[1]
                     + acc[mi][2][rg] * ro_reg[2] + acc[mi][3][rg] * ro_reg[3];
            pd = red16(pd);
            float x0 = x0_l[cand];
            float A = fmaf(kz, pd, -zeta * x0);
            float sq = 0.f;
            #pragma unroll
            for (int ni = 0; ni < 4; ni++) {
                float ttc = fmaf(A, ro_reg[ni], acc[mi][ni][rg]);
                float dd = ttc - th_reg[ni];
                sq = fmaf(dd, dd, sq);
            }
            sq = red16(sq);
            float tt0 = zeta * x0 - zeta * pd;
            float d0 = tt0 - th0;
            float total = sq - d0 * d0;
            if (m == 0) out[b * 256 + cand] = 0.85f - total + bhu + bt_l[cand];
        }
    }
}

extern "C" void kernel_launch(void* const* d_in, const int* in_sizes, int n_in,
                              void* d_out, int out_size, void* d_ws, size_t ws_size,
                              hipStream_t stream) {
    const int*   pos = (const int*)d_in[0];
    const int*   neg = (const int*)d_in[1];
    const float* emb = (const float*)d_in[2];
    const float* bh  = (const float*)d_in[3];
    const float* bt  = (const float*)d_in[4];
    const float* rwh = (const float*)d_in[5];
    const float* bwh = (const float*)d_in[6];
    const float* rwt = (const float*)d_in[7];
    const float* bwt = (const float*)d_in[8];
    float* ws  = (float*)d_ws;
    float* wgp = ws + OFF_W;
    float* thg = ws + OFF_TH;
    float* rog = ws + OFF_RO;
    float* zkg = ws + OFF_ZK;
    float* out = (float*)d_out;

    k01_fused<<<dim3(1024), dim3(256), 0, stream>>>(rwh, rwt, bwt, wgp, rog, zkg);
    k2_th    <<<dim3(256),  dim3(256), 0, stream>>>(pos, emb, wgp, bwh, thg);
    k3_score <<<dim3(1024), dim3(256), 0, stream>>>(pos, neg, emb, bh, bt, wgp,
                                                    thg, rog, zkg, out);
}

// Round 11
// 63.401 us; speedup vs baseline: 1.7099x; 1.0325x over previous
//
#include <hip/hip_runtime.h>
#include <math.h>

#define DM1 63
#define WROW 64
#define RSIZE (DM1*WROW)   // 4032 floats per rel-side matrix
#define VSTR 68            // k01 LDS row stride

typedef float f4 __attribute__((ext_vector_type(4)));
typedef float f32x4 __attribute__((ext_vector_type(4)));
typedef short s16x8 __attribute__((ext_vector_type(8)));
typedef unsigned u32x4 __attribute__((ext_vector_type(4)));

// d_ws float offsets
#define OFF_W   0u                         // f32 W-head: 512 * 4032
#define SZ_W    (512u*RSIZE)
#define OFF_BF  (OFF_W + SZ_W)             // bf16 W-tail frag: 512*8192 u16 (h|l)
#define SZ_BF   (512u*8192u/2u)            // in float units
#define OFF_TH  (OFF_BF + SZ_BF)
#define SZ_TH   (1024u*64u)
#define OFF_RO  (OFF_TH + SZ_TH)
#define SZ_RO   (512u*64u)
#define OFF_ZK  (OFF_RO + SZ_RO)

#define GLLDS(g, l) __builtin_amdgcn_global_load_lds( \
    (const __attribute__((address_space(1))) void*)(const void*)(g), \
    (__attribute__((address_space(3))) void*)(void*)(l), 16, 0, 0)

__device__ __forceinline__ float qreduce(float d) {
    int t = __builtin_amdgcn_mov_dpp(__float_as_int(d), 0xB1, 0xF, 0xF, true);
    d += __int_as_float(t);
    t = __builtin_amdgcn_mov_dpp(__float_as_int(d), 0x4E, 0xF, 0xF, true);
    d += __int_as_float(t);
    return d;
}

__device__ __forceinline__ float red16(float d) {
    int t = __builtin_amdgcn_mov_dpp(__float_as_int(d), 0xB1, 0xF, 0xF, true);
    d += __int_as_float(t);
    t = __builtin_amdgcn_mov_dpp(__float_as_int(d), 0x4E, 0xF, 0xF, true);
    d += __int_as_float(t);
    d += __shfl_xor(d, 4);
    d += __shfl_xor(d, 8);
    return d;
}

// packed f32x2 -> bf16x2 (RNE), low word = first arg
__device__ __forceinline__ unsigned cvtpk(float lo, float hi) {
    unsigned r;
    asm volatile("v_cvt_pk_bf16_f32 %0, %1, %2" : "=v"(r) : "v"(lo), "v"(hi));
    return r;
}

// ---------------- K01: gelu + scale + Householder product (+k_ro on side-1).
// Side 0 (head): write f32 W for k2. Side 1 (tail): write bf16 hi/lo in MFMA
// fragment layout for k3 (converted once per relation, not per block).
#define K1LOAD(V, s) do { const f4* _vp = (const f4*)(vbase + (size_t)(s) * VSTR); \
    V##0 = _vp[0]; V##1 = _vp[1]; V##2 = _vp[2]; V##3 = _vp[3]; } while(0)

#define K1STEP(V) do { \
    f4 q01 = w0*V##0 + w1*V##1; \
    f4 q23 = w2*V##2 + w3*V##3; \
    f4 q = q01 + q23; \
    float d = (q[0] + q[1]) + (q[2] + q[3]); \
    d = qreduce(d); \
    w0 -= d*V##0; w1 -= d*V##1; w2 -= d*V##2; w3 -= d*V##3; } while(0)

__global__ __launch_bounds__(256) void k01_fused(const float* __restrict__ rwh,
                                                 const float* __restrict__ rwt,
                                                 const float* __restrict__ bwt,
                                                 float* __restrict__ wg,
                                                 unsigned short* __restrict__ wbf,
                                                 float* __restrict__ rog,
                                                 float* __restrict__ zkg) {
    int rs = blockIdx.x;
    int side = rs >> 9, r = rs & 511;
    const float* rw = (side ? rwt : rwh) + (size_t)r * 3969;
    __shared__ __align__(16) float vv[64 * VSTR];
    __shared__ float sc[64];
    int tid = threadIdx.x;

    if (side && tid < 64) {
        int c = tid;
        float rov = (c < 63) ? tanhf(bwt[r * 63 + c]) * 0.015625f : 0.f;
        rog[r * 64 + c] = rov;
        float p = rov * rov;
        #pragma unroll
        for (int off = 32; off; off >>= 1) p += __shfl_xor(p, off);
        if (c == 0) {
            float v2 = p;
            float zeta = 1.f / (sqrtf(1.f - v2) + 1e-8f);
            zkg[r * 2]     = zeta;
            zkg[r * 2 + 1] = (zeta - 1.f) / (v2 + 1e-9f);
        }
    }

    for (int idx = tid; idx < 3969; idx += 256) {
        int s = idx / 63, j = idx - s * 63;
        float x = rw[idx];
        vv[s * VSTR + j] = 0.5f * x * (1.f + erff(x * 0.70710678118654752f));
    }
    if (tid < DM1) vv[tid * VSTR + 63] = 0.f;
    __syncthreads();

    if (tid < 252) {
        int s = tid >> 2, p = tid & 3;
        const float* vr = &vv[s * VSTR + p * 16];
        float sum = 0.f;
        #pragma unroll
        for (int j = 0; j < 16; j++) { float v = vr[j]; sum = fmaf(v, v, sum); }
        sum = qreduce(sum);
        if (p == 0) sc[s] = sqrtf(2.f / sum);
    }
    __syncthreads();

    for (int idx = tid; idx < DM1 * 64; idx += 256) {
        int s = idx >> 6, j = idx & 63;
        vv[s * VSTR + j] *= sc[s];
    }
    __syncthreads();

    int lane = tid & 63, wv = tid >> 6;
    int row = wv * 16 + (lane >> 2);
    int p = lane & 3;
    int c0 = p * 16;
    const float* vbase = &vv[c0];

    f4 w0, w1, w2, w3;
    #define IW(k, b) (((b) + (k)) == row ? 1.f : 0.f)
    w0 = (f4){IW(0,c0),    IW(1,c0),    IW(2,c0),    IW(3,c0)};
    w1 = (f4){IW(0,c0+4),  IW(1,c0+4),  IW(2,c0+4),  IW(3,c0+4)};
    w2 = (f4){IW(0,c0+8),  IW(1,c0+8),  IW(2,c0+8),  IW(3,c0+8)};
    w3 = (f4){IW(0,c0+12), IW(1,c0+12), IW(2,c0+12), IW(3,c0+12)};
    #undef IW

    f4 va0,va1,va2,va3, vb0,vb1,vb2,vb3, vc0,vc1,vc2,vc3, vd0,vd1,vd2,vd3;
    K1LOAD(va, 0); K1LOAD(vb, 1); K1LOAD(vc, 2); K1LOAD(vd, 3);
    #pragma unroll 1
    for (int s = 0; s < 56; s += 4) {
        K1STEP(va); K1LOAD(va, s + 4);
        K1STEP(vb); K1LOAD(vb, s + 5);
        K1STEP(vc); K1LOAD(vc, s + 6);
        K1STEP(vd); K1LOAD(vd, s + 7);
    }
    K1STEP(va); K1LOAD(va, 60);
    K1STEP(vb); K1LOAD(vb, 61);
    K1STEP(vc); K1LOAD(vc, 62);
    K1STEP(vd);
    K1STEP(va);
    K1STEP(vb);
    K1STEP(vc);

    if (side == 0) {
        if (row < DM1) {
            f4* wo = (f4*)(wg + (size_t)r * RSIZE + (size_t)row * WROW + c0);
            wo[0] = w0; wo[1] = w1; wo[2] = w2; wo[3] = w3;
        }
    } else {
        // dump W rows to LDS (v-data dead), then emit bf16 hi/lo fragment layout
        __syncthreads();
        {
            f4* vr = (f4*)&vv[row * VSTR + c0];
            vr[0] = w0; vr[1] = w1; vr[2] = w2; vr[3] = w3;  // row 63 dummy, never read
        }
        __syncthreads();
        unsigned short* wb = wbf + (size_t)r * 8192;
        #pragma unroll
        for (int i = 0; i < 2; i++) {
            int gidx = i * 256 + tid;          // u16x8 index; di = gidx*8
            int n  = (gidx >> 7) * 16 + (gidx & 15);
            int k0 = ((gidx >> 6) & 1) * 32 + ((gidx >> 4) & 3) * 8;
            float vals[8];
            #pragma unroll
            for (int e = 0; e < 8; e++) {
                int k = k0 + e;
                vals[e] = (k == 0) ? 0.f : vv[(k - 1) * VSTR + n];
            }
            u32x4 hw, lw;
            #pragma unroll
            for (int e = 0; e < 4; e++) {
                unsigned h = cvtpk(vals[2*e], vals[2*e+1]);
                float h0 = __uint_as_float(h << 16);
                float h1 = __uint_as_float(h & 0xFFFF0000u);
                hw[e] = h;
                lw[e] = cvtpk(vals[2*e] - h0, vals[2*e+1] - h1);
            }
            *(u32x4*)(wb + gidx * 8) = hw;
            *(u32x4*)(wb + 4096 + gidx * 8) = lw;
        }
    }
}

// ---------------- K2: head transform. Wave per b, 4 b's per block.
__global__ __launch_bounds__(256) void k2_th(const int* __restrict__ pos,
                      const float* __restrict__ emb,
                      const float* __restrict__ wg, const float* __restrict__ bwh,
                      float* __restrict__ thg) {
    int tid = threadIdx.x;
    int b = blockIdx.x * 4 + (tid >> 6), c = tid & 63;
    int u = pos[b * 3], r = pos[b * 3 + 1];
    const float* hrow = emb + (size_t)u * 64;
    const float* wr = wg + (size_t)r * RSIZE;
    float xnc = 0.f;
    for (int d = 0; d < DM1; d++) xnc = fmaf(hrow[1 + d], wr[d * WROW + c], xnc);
    float rov = (c < 63) ? tanhf(bwh[r * 63 + c]) * 0.015625f : 0.f;
    float p = rov * rov, q = xnc * rov;
    #pragma unroll
    for (int off = 32; off; off >>= 1) { p += __shfl_xor(p, off); q += __shfl_xor(q, off); }
    float v2 = p, dot = q;
    float zeta = 1.f / (sqrtf(1.f - v2) + 1e-8f);
    float k = (zeta - 1.f) / (v2 + 1e-9f);
    float x0 = hrow[0];
    float val;
    int idx;
    if (c < 63) { val = fmaf(-zeta * x0, rov, xnc) + k * rov * dot; idx = c + 1; }
    else        { val = zeta * x0 - zeta * dot;                      idx = 0;    }
    thg[b * 64 + idx] = val;
}

// ---------------- K3: MFMA scoring; W staged via async global_load_lds (bf16
// fragments pre-built by k01), t staged via cvt_pk.
__global__ __launch_bounds__(256) void k3_score(
    const int* __restrict__ pos, const int* __restrict__ neg,
    const float* __restrict__ emb, const float* __restrict__ bh,
    const float* __restrict__ bt, const unsigned short* __restrict__ wbf,
    const float* __restrict__ thg, const float* __restrict__ rog,
    const float* __restrict__ zkg, float* __restrict__ out) {
    __shared__ __align__(16) unsigned short tf[16384];   // 32 KB [wv][mi][kk][lane*8]
    __shared__ __align__(16) unsigned short wfh[4096];   // 8 KB [ni][kk][lane*8]
    __shared__ __align__(16) unsigned short wfl[4096];   // 8 KB
    __shared__ float x0_l[256];
    __shared__ float bt_l[256];
    __shared__ float th_l[64];
    __shared__ float ro_l[64];
    __shared__ float zk_l[2];

    int b = blockIdx.x, j = threadIdx.x;
    int lane = j & 63, wv = j >> 6;
    int u = pos[b * 3], r = pos[b * 3 + 1];
    int v = (j == 0) ? pos[b * 3 + 2] : neg[b * 255 + j - 1];

    // ---- issue random-row gather first (latency hides under W DMA + staging)
    const float4* tp4 = (const float4*)(emb + (size_t)v * 64);
    f4 trow[16];
    #pragma unroll
    for (int q = 0; q < 16; q++) trow[q] = *(const f4*)(&tp4[q]);
    float btv = bt[v];

    // ---- async W stage: 4 global_load_lds per wave (h:2, l:2), linear lane*16
    {
        const unsigned short* srcb = wbf + (size_t)r * 8192;
        #pragma unroll
        for (int t = 0; t < 2; t++) {
            int tt = 2 * wv + t;
            GLLDS(srcb + tt * 512 + lane * 8,        &wfh[tt * 512]);
            GLLDS(srcb + 4096 + tt * 512 + lane * 8, &wfl[tt * 512]);
        }
    }
    if (j < 64)            th_l[j] = thg[b * 64 + j];
    else if (j < 128)      ro_l[j - 64] = rog[r * 64 + (j - 64)];
    else if (j == 128)     { zk_l[0] = zkg[2 * r]; zk_l[1] = zkg[2 * r + 1]; }

    // ---- convert + store t row into fragment layout (cvt_pk: 2 f32 -> 1 u32)
    {
        int base = wv * 4096 + ((j >> 4) & 3) * 1024 + (j & 15) * 8;
        x0_l[j] = trow[0][0];
        bt_l[j] = tanhf(btv);
        #pragma unroll
        for (int q = 0; q < 16; q += 2) {
            f4 a = trow[q], c2 = trow[q + 1];
            u32x4 pk;
            pk[0] = cvtpk(a[0], a[1]);   pk[1] = cvtpk(a[2], a[3]);
            pk[2] = cvtpk(c2[0], c2[1]); pk[3] = cvtpk(c2[2], c2[3]);
            *(u32x4*)(&tf[base + (q >> 3) * 512 + ((q >> 1) & 3) * 128]) = pk;
        }
    }
    __syncthreads();   // drains vmcnt incl. global_load_lds

    // ---- MFMA: wave wv owns cands [64wv, 64wv+64)
    int g = lane >> 4, m = lane & 15;
    f32x4 acc[4][4] = {};
    #pragma unroll
    for (int kk = 0; kk < 2; kk++) {
        s16x8 bh_[4], bl_[4];
        #pragma unroll
        for (int ni = 0; ni < 4; ni++) {
            bh_[ni] = *(const s16x8*)(&wfh[ni * 1024 + kk * 512 + lane * 8]);
            bl_[ni] = *(const s16x8*)(&wfl[ni * 1024 + kk * 512 + lane * 8]);
        }
        #pragma unroll
        for (int mi = 0; mi < 4; mi++) {
            s16x8 af = *(const s16x8*)(&tf[wv * 4096 + mi * 1024 + kk * 512 + lane * 8]);
            #pragma unroll
            for (int ni = 0; ni < 4; ni++) {
                acc[mi][ni] = __builtin_amdgcn_mfma_f32_16x16x32_bf16(af, bh_[ni], acc[mi][ni], 0, 0, 0);
                acc[mi][ni] = __builtin_amdgcn_mfma_f32_16x16x32_bf16(af, bl_[ni], acc[mi][ni], 0, 0, 0);
            }
        }
    }

    // ---- epilogue: cand = 64wv+16mi+4g+rg, col = 16ni+m
    float zeta = zk_l[0], kz = zk_l[1];
    float th0 = th_l[0];
    float bhu = tanhf(bh[u]);
    float ro_reg[4], th_reg[4];
    #pragma unroll
    for (int ni = 0; ni < 4; ni++) {
        int col = 16 * ni + m;
        ro_reg[ni] = ro_l[col];
        th_reg[ni] = (col == 63) ? 0.f : th_l[1 + col];
    }
    #pragma unroll
    for (int mi = 0; mi < 4; mi++) {
        #pragma unroll
        for (int rg = 0; rg < 4; rg++) {
            int cand = 64 * wv + 16 * mi + 4 * g + rg;
            float pd = acc[mi][0][rg] * ro_reg[0] + acc[mi][1][rg] * ro_reg[1]
                     + acc[mi][2][rg] * ro_reg[2] + acc[mi][3][rg] * ro_reg[3];
            pd = red16(pd);
            float x0 = x0_l[cand];
            float A = fmaf(kz, pd, -zeta * x0);
            float sq = 0.f;
            #pragma unroll
            for (int ni = 0; ni < 4; ni++) {
                float ttc = fmaf(A, ro_reg[ni], acc[mi][ni][rg]);
                float dd = ttc - th_reg[ni];
                sq = fmaf(dd, dd, sq);
            }
            sq = red16(sq);
            float tt0 = zeta * x0 - zeta * pd;
            float d0 = tt0 - th0;
            float total = sq - d0 * d0;
            if (m == 0) out[b * 256 + cand] = 0.85f - total + bhu + bt_l[cand];
        }
    }
}

extern "C" void kernel_launch(void* const* d_in, const int* in_sizes, int n_in,
                              void* d_out, int out_size, void* d_ws, size_t ws_size,
                              hipStream_t stream) {
    const int*   pos = (const int*)d_in[0];
    const int*   neg = (const int*)d_in[1];
    const float* emb = (const float*)d_in[2];
    const float* bh  = (const float*)d_in[3];
    const float* bt  = (const float*)d_in[4];
    const float* rwh = (const float*)d_in[5];
    const float* bwh = (const float*)d_in[6];
    const float* rwt = (const float*)d_in[7];
    const float* bwt = (const float*)d_in[8];
    float* ws  = (float*)d_ws;
    float* wgp = ws + OFF_W;
    unsigned short* wbf = (unsigned short*)(ws + OFF_BF);
    float* thg = ws + OFF_TH;
    float* rog = ws + OFF_RO;
    float* zkg = ws + OFF_ZK;
    float* out = (float*)d_out;

    k01_fused<<<dim3(1024), dim3(256), 0, stream>>>(rwh, rwt, bwt, wgp, wbf, rog, zkg);
    k2_th    <<<dim3(256),  dim3(256), 0, stream>>>(pos, emb, wgp, bwh, thg);
    k3_score <<<dim3(1024), dim3(256), 0, stream>>>(pos, neg, emb, bh, bt, wbf,
                                                    thg, rog, zkg, out);
}

// Round 12
// 52.820 us; speedup vs baseline: 2.0525x; 1.2003x over previous
//
#include <hip/hip_runtime.h>
#include <math.h>

#define DM1 63
#define WROW 64
#define RSIZE (DM1*WROW)
#define VSTR 68            // k01 LDS row stride

typedef float f4 __attribute__((ext_vector_type(4)));
typedef float f32x4 __attribute__((ext_vector_type(4)));
typedef short s16x8 __attribute__((ext_vector_type(8)));
typedef unsigned u32x4 __attribute__((ext_vector_type(4)));

// d_ws float offsets
#define OFF_BF  0u                          // bf16 W-tail frags: 512*8192 u16 (h|l)
#define SZ_BF   (512u*8192u/2u)
#define OFF_TH  (OFF_BF + SZ_BF)
#define SZ_TH   (1024u*64u)
#define OFF_RO  (OFF_TH + SZ_TH)
#define SZ_RO   (512u*64u)
#define OFF_ZK  (OFF_RO + SZ_RO)

__device__ __forceinline__ float qreduce(float d) {
    int t = __builtin_amdgcn_mov_dpp(__float_as_int(d), 0xB1, 0xF, 0xF, true);
    d += __int_as_float(t);
    t = __builtin_amdgcn_mov_dpp(__float_as_int(d), 0x4E, 0xF, 0xF, true);
    d += __int_as_float(t);
    return d;
}

// 16-lane sum, all-DPP (quad xor1, xor2, row_ror:4, row_ror:8) — no LDS pipe
__device__ __forceinline__ float red16(float d) {
    d += __int_as_float(__builtin_amdgcn_mov_dpp(__float_as_int(d), 0xB1,  0xF, 0xF, true));
    d += __int_as_float(__builtin_amdgcn_mov_dpp(__float_as_int(d), 0x4E,  0xF, 0xF, true));
    d += __int_as_float(__builtin_amdgcn_mov_dpp(__float_as_int(d), 0x124, 0xF, 0xF, true));
    d += __int_as_float(__builtin_amdgcn_mov_dpp(__float_as_int(d), 0x128, 0xF, 0xF, true));
    return d;
}

__device__ __forceinline__ unsigned cvtpk(float lo, float hi) {
    unsigned r;
    asm volatile("v_cvt_pk_bf16_f32 %0, %1, %2" : "=v"(r) : "v"(lo), "v"(hi));
    return r;
}

// ---------------- K01: gelu + scale + Householder (+k_ro, +head-th on side-0).
#define K1LOAD(V, s) do { const f4* _vp = (const f4*)(vbase + (size_t)(s) * VSTR); \
    V##0 = _vp[0]; V##1 = _vp[1]; V##2 = _vp[2]; V##3 = _vp[3]; } while(0)

#define K1STEP(V) do { \
    f4 q01 = w0*V##0 + w1*V##1; \
    f4 q23 = w2*V##2 + w3*V##3; \
    f4 q = q01 + q23; \
    float d = (q[0] + q[1]) + (q[2] + q[3]); \
    d = qreduce(d); \
    w0 -= d*V##0; w1 -= d*V##1; w2 -= d*V##2; w3 -= d*V##3; } while(0)

__global__ __launch_bounds__(256) void k01_fused(const float* __restrict__ rwh,
                                                 const float* __restrict__ rwt,
                                                 const float* __restrict__ bwh,
                                                 const float* __restrict__ bwt,
                                                 const int* __restrict__ pos,
                                                 const float* __restrict__ emb,
                                                 unsigned short* __restrict__ wbf,
                                                 float* __restrict__ thg,
                                                 float* __restrict__ rog,
                                                 float* __restrict__ zkg) {
    int rs = blockIdx.x;
    int side = rs >> 9, r = rs & 511;
    const float* rw = (side ? rwt : rwh) + (size_t)r * 3969;
    __shared__ __align__(16) float vv[64 * VSTR];
    __shared__ float sc[64];
    __shared__ int blist[64];
    __shared__ int bcnt;
    int tid = threadIdx.x;
    if (tid == 0) bcnt = 0;

    if (side && tid < 64) {
        int c = tid;
        float rov = (c < 63) ? tanhf(bwt[r * 63 + c]) * 0.015625f : 0.f;
        rog[r * 64 + c] = rov;
        float p = rov * rov;
        #pragma unroll
        for (int off = 32; off; off >>= 1) p += __shfl_xor(p, off);
        if (c == 0) {
            float v2 = p;
            float zeta = 1.f / (sqrtf(1.f - v2) + 1e-8f);
            zkg[r * 2]     = zeta;
            zkg[r * 2 + 1] = (zeta - 1.f) / (v2 + 1e-9f);
        }
    }

    for (int idx = tid; idx < 3969; idx += 256) {
        int s = idx / 63, j = idx - s * 63;
        float x = rw[idx];
        vv[s * VSTR + j] = 0.5f * x * (1.f + erff(x * 0.70710678118654752f));
    }
    if (tid < DM1) vv[tid * VSTR + 63] = 0.f;
    __syncthreads();

    if (tid < 252) {
        int s = tid >> 2, p = tid & 3;
        const float* vr = &vv[s * VSTR + p * 16];
        float sum = 0.f;
        #pragma unroll
        for (int j = 0; j < 16; j++) { float v = vr[j]; sum = fmaf(v, v, sum); }
        sum = qreduce(sum);
        if (p == 0) sc[s] = sqrtf(2.f / sum);
    }
    __syncthreads();

    for (int idx = tid; idx < DM1 * 64; idx += 256) {
        int s = idx >> 6, j = idx & 63;
        vv[s * VSTR + j] *= sc[s];
    }
    __syncthreads();

    int lane = tid & 63, wv = tid >> 6;
    int row = wv * 16 + (lane >> 2);
    int p = lane & 3;
    int c0 = p * 16;
    const float* vbase = &vv[c0];

    f4 w0, w1, w2, w3;
    #define IW(k, b) (((b) + (k)) == row ? 1.f : 0.f)
    w0 = (f4){IW(0,c0),    IW(1,c0),    IW(2,c0),    IW(3,c0)};
    w1 = (f4){IW(0,c0+4),  IW(1,c0+4),  IW(2,c0+4),  IW(3,c0+4)};
    w2 = (f4){IW(0,c0+8),  IW(1,c0+8),  IW(2,c0+8),  IW(3,c0+8)};
    w3 = (f4){IW(0,c0+12), IW(1,c0+12), IW(2,c0+12), IW(3,c0+12)};
    #undef IW

    f4 va0,va1,va2,va3, vb0,vb1,vb2,vb3, vc0,vc1,vc2,vc3, vd0,vd1,vd2,vd3;
    K1LOAD(va, 0); K1LOAD(vb, 1); K1LOAD(vc, 2); K1LOAD(vd, 3);
    #pragma unroll 1
    for (int s = 0; s < 56; s += 4) {
        K1STEP(va); K1LOAD(va, s + 4);
        K1STEP(vb); K1LOAD(vb, s + 5);
        K1STEP(vc); K1LOAD(vc, s + 6);
        K1STEP(vd); K1LOAD(vd, s + 7);
    }
    K1STEP(va); K1LOAD(va, 60);
    K1STEP(vb); K1LOAD(vb, 61);
    K1STEP(vc); K1LOAD(vc, 62);
    K1STEP(vd);
    K1STEP(va);
    K1STEP(vb);
    K1STEP(vc);

    // dump W rows to LDS (v-data dead)
    __syncthreads();
    {
        f4* vr = (f4*)&vv[row * VSTR + c0];
        vr[0] = w0; vr[1] = w1; vr[2] = w2; vr[3] = w3;   // row 63 dummy, never read
    }
    __syncthreads();

    if (side == 0) {
        // ---- head side: compute th for every batch row using this relation
        for (int i = tid; i < 1024; i += 256)
            if (pos[3 * i + 1] == r) { int s = atomicAdd(&bcnt, 1); if (s < 64) blist[s] = i; }
        __syncthreads();
        int cnt = bcnt < 64 ? bcnt : 64;
        if (cnt) {
            int c = lane;
            float rov = (c < 63) ? tanhf(bwh[r * 63 + c]) * 0.015625f : 0.f;
            float pp = rov * rov;
            #pragma unroll
            for (int off = 32; off; off >>= 1) pp += __shfl_xor(pp, off);
            float v2 = pp;
            float zeta = 1.f / (sqrtf(1.f - v2) + 1e-8f);
            float kz = (zeta - 1.f) / (v2 + 1e-9f);
            for (int e = wv; e < cnt; e += 4) {
                int b = blist[e];
                int u = pos[3 * b];
                const float* hrow = emb + (size_t)u * 64;   // wave-uniform
                float xnc = 0.f;
                for (int d = 0; d < DM1; d++) xnc = fmaf(hrow[1 + d], vv[d * VSTR + c], xnc);
                float q = xnc * rov;
                #pragma unroll
                for (int off = 32; off; off >>= 1) q += __shfl_xor(q, off);
                float dot = q;
                float x0 = hrow[0];
                float val; int idx;
                if (c < 63) { val = fmaf(-zeta * x0, rov, xnc) + kz * rov * dot; idx = c + 1; }
                else        { val = zeta * x0 - zeta * dot;                       idx = 0;    }
                thg[b * 64 + idx] = val;
            }
        }
    } else {
        // ---- tail side: emit bf16 hi/lo fragment layout once per relation
        unsigned short* wb = wbf + (size_t)r * 8192;
        #pragma unroll
        for (int i = 0; i < 2; i++) {
            int gidx = i * 256 + tid;          // u16x8 index
            int n  = (gidx >> 7) * 16 + (gidx & 15);
            int k0 = ((gidx >> 6) & 1) * 32 + ((gidx >> 4) & 3) * 8;
            float vals[8];
            #pragma unroll
            for (int e = 0; e < 8; e++) {
                int k = k0 + e;
                vals[e] = (k == 0) ? 0.f : vv[(k - 1) * VSTR + n];
            }
            u32x4 hw, lw;
            #pragma unroll
            for (int e = 0; e < 4; e++) {
                unsigned h = cvtpk(vals[2*e], vals[2*e+1]);
                float h0 = __uint_as_float(h << 16);
                float h1 = __uint_as_float(h & 0xFFFF0000u);
                hw[e] = h;
                lw[e] = cvtpk(vals[2*e] - h0, vals[2*e+1] - h1);
            }
            *(u32x4*)(wb + gidx * 8) = hw;
            *(u32x4*)(wb + 4096 + gidx * 8) = lw;
        }
    }
}

// ---------------- K3: MFMA scoring; W fragments read global->VGPR (coalesced,
// L1-broadcast across waves); t staged in LDS fragment layout. 35 KB -> 4 blk/CU.
__global__ __launch_bounds__(256, 4) void k3_score(
    const int* __restrict__ pos, const int* __restrict__ neg,
    const float* __restrict__ emb, const float* __restrict__ bh,
    const float* __restrict__ bt, const unsigned short* __restrict__ wbf,
    const float* __restrict__ thg, const float* __restrict__ rog,
    const float* __restrict__ zkg, float* __restrict__ out) {
    __shared__ __align__(16) unsigned short tf[16384];   // 32 KB [wv][mi][kk][lane*8]
    __shared__ float x0_l[256];
    __shared__ float bt_l[256];
    __shared__ float th_l[64];
    __shared__ float ro_l[64];
    __shared__ float zk_l[2];

    int b = blockIdx.x, j = threadIdx.x;
    int lane = j & 63, wv = j >> 6;
    int u = pos[b * 3], r = pos[b * 3 + 1];
    int v = (j == 0) ? pos[b * 3 + 2] : neg[b * 255 + j - 1];

    // issue random-row gather first
    const float4* tp4 = (const float4*)(emb + (size_t)v * 64);
    f4 trow[16];
    #pragma unroll
    for (int q = 0; q < 16; q++) trow[q] = *(const f4*)(&tp4[q]);
    float btv = bt[v];

    if (j < 64)            th_l[j] = thg[b * 64 + j];
    else if (j < 128)      ro_l[j - 64] = rog[r * 64 + (j - 64)];
    else if (j == 128)     { zk_l[0] = zkg[2 * r]; zk_l[1] = zkg[2 * r + 1]; }

    // convert + store t row into fragment layout
    {
        int base = wv * 4096 + ((j >> 4) & 3) * 1024 + (j & 15) * 8;
        x0_l[j] = trow[0][0];
        bt_l[j] = tanhf(btv);
        #pragma unroll
        for (int q = 0; q < 16; q += 2) {
            f4 a = trow[q], c2 = trow[q + 1];
            u32x4 pk;
            pk[0] = cvtpk(a[0], a[1]);   pk[1] = cvtpk(a[2], a[3]);
            pk[2] = cvtpk(c2[0], c2[1]); pk[3] = cvtpk(c2[2], c2[3]);
            *(u32x4*)(&tf[base + (q >> 3) * 512 + ((q >> 1) & 3) * 128]) = pk;
        }
    }
    __syncthreads();

    // MFMA: B fragments straight from global (fragment-linear wbf)
    int g = lane >> 4, m = lane & 15;
    const s16x8* wb8 = (const s16x8*)(wbf + (size_t)r * 8192);
    f32x4 acc[4][4] = {};
    #pragma unroll
    for (int kk = 0; kk < 2; kk++) {
        s16x8 bh_[4], bl_[4];
        #pragma unroll
        for (int ni = 0; ni < 4; ni++) {
            bh_[ni] = wb8[ni * 128 + kk * 64 + lane];
            bl_[ni] = wb8[512 + ni * 128 + kk * 64 + lane];
        }
        #pragma unroll
        for (int mi = 0; mi < 4; mi++) {
            s16x8 af = *(const s16x8*)(&tf[wv * 4096 + mi * 1024 + kk * 512 + lane * 8]);
            #pragma unroll
            for (int ni = 0; ni < 4; ni++) {
                acc[mi][ni] = __builtin_amdgcn_mfma_f32_16x16x32_bf16(af, bh_[ni], acc[mi][ni], 0, 0, 0);
                acc[mi][ni] = __builtin_amdgcn_mfma_f32_16x16x32_bf16(af, bl_[ni], acc[mi][ni], 0, 0, 0);
            }
        }
    }

    // epilogue: cand = 64wv+16mi+4g+rg, col = 16ni+m
    float zeta = zk_l[0], kz = zk_l[1];
    float th0 = th_l[0];
    float bhu = tanhf(bh[u]);
    float ro_reg[4], th_reg[4];
    #pragma unroll
    for (int ni = 0; ni < 4; ni++) {
        int col = 16 * ni + m;
        ro_reg[ni] = ro_l[col];
        th_reg[ni] = (col == 63) ? 0.f : th_l[1 + col];
    }
    #pragma unroll
    for (int mi = 0; mi < 4; mi++) {
        #pragma unroll
        for (int rg = 0; rg < 4; rg++) {
            int cand = 64 * wv + 16 * mi + 4 * g + rg;
            float pd = acc[mi][0][rg] * ro_reg[0] + acc[mi][1][rg] * ro_reg[1]
                     + acc[mi][2][rg] * ro_reg[2] + acc[mi][3][rg] * ro_reg[3];
            pd = red16(pd);
            float x0 = x0_l[cand];
            float A = fmaf(kz, pd, -zeta * x0);
            float sq = 0.f;
            #pragma unroll
            for (int ni = 0; ni < 4; ni++) {
                float ttc = fmaf(A, ro_reg[ni], acc[mi][ni][rg]);
                float dd = ttc - th_reg[ni];
                sq = fmaf(dd, dd, sq);
            }
            sq = red16(sq);
            float tt0 = zeta * x0 - zeta * pd;
            float d0 = tt0 - th0;
            float total = sq - d0 * d0;
            if (m == 0) out[b * 256 + cand] = 0.85f - total + bhu + bt_l[cand];
        }
    }
}

extern "C" void kernel_launch(void* const* d_in, const int* in_sizes, int n_in,
                              void* d_out, int out_size, void* d_ws, size_t ws_size,
                              hipStream_t stream) {
    const int*   pos = (const int*)d_in[0];
    const int*   neg = (const int*)d_in[1];
    const float* emb = (const float*)d_in[2];
    const float* bh  = (const float*)d_in[3];
    const float* bt  = (const float*)d_in[4];
    const float* rwh = (const float*)d_in[5];
    const float* bwh = (const float*)d_in[6];
    const float* rwt = (const float*)d_in[7];
    const float* bwt = (const float*)d_in[8];
    float* ws  = (float*)d_ws;
    unsigned short* wbf = (unsigned short*)(ws + OFF_BF);
    float* thg = ws + OFF_TH;
    float* rog = ws + OFF_RO;
    float* zkg = ws + OFF_ZK;
    float* out = (float*)d_out;

    k01_fused<<<dim3(1024), dim3(256), 0, stream>>>(rwh, rwt, bwh, bwt, pos, emb,
                                                    wbf, thg, rog, zkg);
    k3_score <<<dim3(1024), dim3(256), 0, stream>>>(pos, neg, emb, bh, bt, wbf,
                                                    thg, rog, zkg, out);
}